// Round 5
// baseline (211.998 us; speedup 1.0000x reference)
//
#include <hip/hip_runtime.h>
#include <hip/hip_bf16.h>

#define N_NODES 100000
#define N_EDGES 3200000
#define IN_F 256
#define OUT_F 128

typedef __attribute__((ext_vector_type(8))) short bf16x8;
typedef __attribute__((ext_vector_type(4))) float f32x4;

__device__ __forceinline__ unsigned short f2bf(float f) {
    unsigned int u = __float_as_uint(f);
    u += 0x7fffu + ((u >> 16) & 1u);   // round-to-nearest-even
    return (unsigned short)(u >> 16);
}

// ---- Kernel 0: W [256][128] f32 -> Wt [128][256] bf16 (transpose+convert) ----
__global__ void k_wt(const float* __restrict__ W, unsigned short* __restrict__ Wt) {
    int idx = blockIdx.x * 256 + threadIdx.x;
    if (idx >= IN_F * OUT_F) return;
    int k = idx >> 7;          // 0..255
    int c = idx & 127;         // 0..127
    Wt[c * IN_F + k] = f2bf(W[idx]);
}

// ---- Kernel 1: CSR row_ptr from sorted edge_row ----
__global__ void k_rowptr(const int* __restrict__ erow, int* __restrict__ row_ptr) {
    int e = blockIdx.x * 256 + threadIdx.x;
    if (e >= N_EDGES) return;
    int r = erow[e];
    int rprev = (e == 0) ? -1 : erow[e - 1];
    for (int rr = rprev + 1; rr <= r; ++rr) row_ptr[rr] = e;
    if (e == N_EDGES - 1) {
        for (int rr = r + 1; rr <= N_NODES; ++rr) row_ptr[rr] = N_EDGES;
    }
}

// ---- Kernel 2: H = tanh(A @ W) in bf16. 128x128 tile, 4 waves (2x2), no LDS ----
__global__ __launch_bounds__(256) void k_gemm(const float* __restrict__ A,
                                              const unsigned short* __restrict__ Wt,
                                              unsigned short* __restrict__ H,
                                              const int* __restrict__ activep) {
    const int tid  = threadIdx.x;
    const int lane = tid & 63;
    const int wid  = tid >> 6;
    const int wr   = wid >> 1;   // 0..1 row-half
    const int wc   = wid & 1;    // 0..1 col-half
    const int brow = blockIdx.x * 128;
    const int l15  = lane & 15;
    const int lk   = (lane >> 4) * 8;  // k-offset of this lane's 8 elems

    f32x4 acc[4][4] = {};

    for (int k0 = 0; k0 < IN_F; k0 += 32) {
        bf16x8 a[4], b[4];
        #pragma unroll
        for (int i = 0; i < 4; ++i) {
            int row = brow + wr * 64 + i * 16 + l15;
            if (row > N_NODES - 1) row = N_NODES - 1;   // clamp OOB reads
            const float* p = A + (long)row * IN_F + k0 + lk;
            float4 f0 = *(const float4*)(p);
            float4 f1 = *(const float4*)(p + 4);
            bf16x8 v;
            v[0] = (short)f2bf(f0.x); v[1] = (short)f2bf(f0.y);
            v[2] = (short)f2bf(f0.z); v[3] = (short)f2bf(f0.w);
            v[4] = (short)f2bf(f1.x); v[5] = (short)f2bf(f1.y);
            v[6] = (short)f2bf(f1.z); v[7] = (short)f2bf(f1.w);
            a[i] = v;
        }
        #pragma unroll
        for (int n = 0; n < 4; ++n) {
            int col = wc * 64 + n * 16 + l15;
            b[n] = *(const bf16x8*)(Wt + col * IN_F + k0 + lk);
        }
        #pragma unroll
        for (int i = 0; i < 4; ++i)
            #pragma unroll
            for (int n = 0; n < 4; ++n)
                acc[i][n] = __builtin_amdgcn_mfma_f32_16x16x32_bf16(a[i], b[n], acc[i][n], 0, 0, 0);
    }

    const int act = *activep;
    // C/D layout: col = lane&15, row = (lane>>4)*4 + reg   [m89-verified]
    #pragma unroll
    for (int i = 0; i < 4; ++i) {
        #pragma unroll
        for (int n = 0; n < 4; ++n) {
            #pragma unroll
            for (int r = 0; r < 4; ++r) {
                int row = brow + wr * 64 + i * 16 + (lane >> 4) * 4 + r;
                int col = wc * 64 + n * 16 + l15;
                if (row < N_NODES) {
                    float v = acc[i][n][r];
                    if (act) v = tanhf(v);
                    H[(long)row * OUT_F + col] = f2bf(v);
                }
            }
        }
    }
}

// ---- Kernel 3: SpMM. One wave per row; 32 edges per iteration.
//      Slot q (lane>>4) owns 8 CONSECUTIVE edges -> edge idx/val load as
//      2x int4 + 2x float4; 8 independent uint4 gathers (8KB/wave) issued
//      before any FMA. Value-predicated head/tail.
//      Slot-tail near N_EDGES: per-element clamped loads so value/column/
//      validity all refer to the SAME edge index (fixes R4 bug).
//      shfl_xor(16/32) butterfly merges the 4 slots at row end. ----
__global__ __launch_bounds__(256, 4) void k_spmm(const int* __restrict__ row_ptr,
                                                 const int* __restrict__ ecol,
                                                 const float* __restrict__ eval,
                                                 const unsigned int* __restrict__ h32, // bf16x2 per dword
                                                 float* __restrict__ out) {
    const int lane = threadIdx.x & 63;
    const int w    = threadIdx.x >> 6;
    const int r    = blockIdx.x * 4 + w;
    if (r >= N_NODES) return;

    const int q  = lane >> 4;         // edge slot 0..3 (8 consecutive edges each)
    const int dq = (lane & 15) * 4;   // dword offset within h row (0..60)

    const int s = __builtin_amdgcn_readfirstlane(row_ptr[r]);
    const int e = __builtin_amdgcn_readfirstlane(row_ptr[r + 1]);

    const unsigned int* hq = h32 + dq;

    float f0 = 0.f, f1 = 0.f, f2 = 0.f, f3 = 0.f;
    float f4 = 0.f, f5 = 0.f, f6 = 0.f, f7 = 0.f;

    const int j0 = s & ~3;            // 16B-align all int4/float4 edge loads
    for (int j = j0; j < e; j += 32) {
        const int b = j + q * 8;      // this slot's 8 edges

        int4   c0, c1;
        float4 v0, v1;
        if (b + 8 <= N_EDGES) {       // fast path: aligned vector loads at b
            c0 = *(const int4*)(ecol + b);
            c1 = *(const int4*)(ecol + b + 4);
            v0 = *(const float4*)(eval + b);
            v1 = *(const float4*)(eval + b + 4);
        } else {                      // rare: last iteration of last row only
            int idx[8];
            #pragma unroll
            for (int t = 0; t < 8; ++t) idx[t] = min(b + t, N_EDGES - 1);
            c0.x = ecol[idx[0]]; c0.y = ecol[idx[1]]; c0.z = ecol[idx[2]]; c0.w = ecol[idx[3]];
            c1.x = ecol[idx[4]]; c1.y = ecol[idx[5]]; c1.z = ecol[idx[6]]; c1.w = ecol[idx[7]];
            v0.x = eval[idx[0]]; v0.y = eval[idx[1]]; v0.z = eval[idx[2]]; v0.w = eval[idx[3]];
            v1.x = eval[idx[4]]; v1.y = eval[idx[5]]; v1.z = eval[idx[6]]; v1.w = eval[idx[7]];
        }

        // validity from edge index b+t (for valid t, loaded data IS edge b+t)
        float vv[8];
        vv[0] = (b + 0 >= s && b + 0 < e) ? v0.x : 0.f;
        vv[1] = (b + 1 >= s && b + 1 < e) ? v0.y : 0.f;
        vv[2] = (b + 2 >= s && b + 2 < e) ? v0.z : 0.f;
        vv[3] = (b + 3 >= s && b + 3 < e) ? v0.w : 0.f;
        vv[4] = (b + 4 >= s && b + 4 < e) ? v1.x : 0.f;
        vv[5] = (b + 5 >= s && b + 5 < e) ? v1.y : 0.f;
        vv[6] = (b + 6 >= s && b + 6 < e) ? v1.z : 0.f;
        vv[7] = (b + 7 >= s && b + 7 < e) ? v1.w : 0.f;

        uint4 g[8];
        g[0] = *(const uint4*)(hq + (((unsigned)c0.x) << 6));
        g[1] = *(const uint4*)(hq + (((unsigned)c0.y) << 6));
        g[2] = *(const uint4*)(hq + (((unsigned)c0.z) << 6));
        g[3] = *(const uint4*)(hq + (((unsigned)c0.w) << 6));
        g[4] = *(const uint4*)(hq + (((unsigned)c1.x) << 6));
        g[5] = *(const uint4*)(hq + (((unsigned)c1.y) << 6));
        g[6] = *(const uint4*)(hq + (((unsigned)c1.z) << 6));
        g[7] = *(const uint4*)(hq + (((unsigned)c1.w) << 6));

        #pragma unroll
        for (int t = 0; t < 8; ++t) {
            const float v = vv[t];
            f0 = fmaf(v, __uint_as_float(g[t].x << 16), f0);
            f1 = fmaf(v, __uint_as_float(g[t].x & 0xffff0000u), f1);
            f2 = fmaf(v, __uint_as_float(g[t].y << 16), f2);
            f3 = fmaf(v, __uint_as_float(g[t].y & 0xffff0000u), f3);
            f4 = fmaf(v, __uint_as_float(g[t].z << 16), f4);
            f5 = fmaf(v, __uint_as_float(g[t].z & 0xffff0000u), f5);
            f6 = fmaf(v, __uint_as_float(g[t].w << 16), f6);
            f7 = fmaf(v, __uint_as_float(g[t].w & 0xffff0000u), f7);
        }
    }

    // reduce the 4 edge slots: lanes l, l+16, l+32, l+48 hold the same columns
    #pragma unroll
    for (int mask = 16; mask <= 32; mask <<= 1) {
        f0 += __shfl_xor(f0, mask);
        f1 += __shfl_xor(f1, mask);
        f2 += __shfl_xor(f2, mask);
        f3 += __shfl_xor(f3, mask);
        f4 += __shfl_xor(f4, mask);
        f5 += __shfl_xor(f5, mask);
        f6 += __shfl_xor(f6, mask);
        f7 += __shfl_xor(f7, mask);
    }

    if (q == 0) {
        float* dst = out + (long)r * OUT_F + dq * 2;  // dq*2 = (lane&15)*8 cols
        float4 o0; o0.x = f0; o0.y = f1; o0.z = f2; o0.w = f3;
        float4 o1; o1.x = f4; o1.y = f5; o1.z = f6; o1.w = f7;
        *(float4*)dst       = o0;
        *(float4*)(dst + 4) = o1;
    }
}

extern "C" void kernel_launch(void* const* d_in, const int* in_sizes, int n_in,
                              void* d_out, int out_size, void* d_ws, size_t ws_size,
                              hipStream_t stream) {
    const float* features = (const float*)d_in[0];
    const float* weight   = (const float*)d_in[1];
    const int*   erow     = (const int*)d_in[2];
    const int*   ecol     = (const int*)d_in[3];
    const float* evalp    = (const float*)d_in[4];
    const int*   activep  = (const int*)d_in[5];
    float* out = (float*)d_out;

    char* ws = (char*)d_ws;
    unsigned short* H  = (unsigned short*)ws;                         // 25,600,000 B
    unsigned short* Wt = (unsigned short*)(ws + 25600000);            //     65,536 B
    int* row_ptr       = (int*)(ws + 25600000 + 65536);               //    400,004 B

    k_wt    <<<128, 256, 0, stream>>>(weight, Wt);
    k_rowptr<<<(N_EDGES + 255) / 256, 256, 0, stream>>>(erow, row_ptr);
    k_gemm  <<<(N_NODES + 127) / 128, 256, 0, stream>>>(features, Wt, H, activep);
    k_spmm  <<<(N_NODES + 3) / 4, 256, 0, stream>>>(row_ptr, ecol, evalp,
                                                    (const unsigned int*)H, out);
}

// Round 6
// 201.623 us; speedup vs baseline: 1.0515x; 1.0515x over previous
//
#include <hip/hip_runtime.h>
#include <hip/hip_bf16.h>

#define N_NODES 100000
#define N_EDGES 3200000
#define IN_F 256
#define OUT_F 128

typedef __attribute__((ext_vector_type(8))) short bf16x8;
typedef __attribute__((ext_vector_type(4))) float f32x4;
typedef __attribute__((ext_vector_type(4))) unsigned int u32x4;

__device__ __forceinline__ unsigned short f2bf(float f) {
    unsigned int u = __float_as_uint(f);
    u += 0x7fffu + ((u >> 16) & 1u);   // round-to-nearest-even
    return (unsigned short)(u >> 16);
}

// ---- Kernel 0: W [256][128] f32 -> Wt [128][256] bf16 (transpose+convert) ----
__global__ void k_wt(const float* __restrict__ W, unsigned short* __restrict__ Wt) {
    int idx = blockIdx.x * 256 + threadIdx.x;
    if (idx >= IN_F * OUT_F) return;
    int k = idx >> 7;          // 0..255
    int c = idx & 127;         // 0..127
    Wt[c * IN_F + k] = f2bf(W[idx]);
}

// ---- Kernel 1: CSR row_ptr from sorted edge_row ----
__global__ void k_rowptr(const int* __restrict__ erow, int* __restrict__ row_ptr) {
    int e = blockIdx.x * 256 + threadIdx.x;
    if (e >= N_EDGES) return;
    int r = erow[e];
    int rprev = (e == 0) ? -1 : erow[e - 1];
    for (int rr = rprev + 1; rr <= r; ++rr) row_ptr[rr] = e;
    if (e == N_EDGES - 1) {
        for (int rr = r + 1; rr <= N_NODES; ++rr) row_ptr[rr] = N_EDGES;
    }
}

// ---- Kernel 2: H = tanh(A @ W) in bf16. 128x128 tile, 4 waves (2x2), no LDS ----
__global__ __launch_bounds__(256) void k_gemm(const float* __restrict__ A,
                                              const unsigned short* __restrict__ Wt,
                                              unsigned short* __restrict__ H,
                                              const int* __restrict__ activep) {
    const int tid  = threadIdx.x;
    const int lane = tid & 63;
    const int wid  = tid >> 6;
    const int wr   = wid >> 1;   // 0..1 row-half
    const int wc   = wid & 1;    // 0..1 col-half
    const int brow = blockIdx.x * 128;
    const int l15  = lane & 15;
    const int lk   = (lane >> 4) * 8;  // k-offset of this lane's 8 elems

    f32x4 acc[4][4] = {};

    for (int k0 = 0; k0 < IN_F; k0 += 32) {
        bf16x8 a[4], b[4];
        #pragma unroll
        for (int i = 0; i < 4; ++i) {
            int row = brow + wr * 64 + i * 16 + l15;
            if (row > N_NODES - 1) row = N_NODES - 1;   // clamp OOB reads
            const float* p = A + (long)row * IN_F + k0 + lk;
            float4 f0 = *(const float4*)(p);
            float4 f1 = *(const float4*)(p + 4);
            bf16x8 v;
            v[0] = (short)f2bf(f0.x); v[1] = (short)f2bf(f0.y);
            v[2] = (short)f2bf(f0.z); v[3] = (short)f2bf(f0.w);
            v[4] = (short)f2bf(f1.x); v[5] = (short)f2bf(f1.y);
            v[6] = (short)f2bf(f1.z); v[7] = (short)f2bf(f1.w);
            a[i] = v;
        }
        #pragma unroll
        for (int n = 0; n < 4; ++n) {
            int col = wc * 64 + n * 16 + l15;
            b[n] = *(const bf16x8*)(Wt + col * IN_F + k0 + lk);
        }
        #pragma unroll
        for (int i = 0; i < 4; ++i)
            #pragma unroll
            for (int n = 0; n < 4; ++n)
                acc[i][n] = __builtin_amdgcn_mfma_f32_16x16x32_bf16(a[i], b[n], acc[i][n], 0, 0, 0);
    }

    const int act = *activep;
    // C/D layout: col = lane&15, row = (lane>>4)*4 + reg   [m89-verified]
    #pragma unroll
    for (int i = 0; i < 4; ++i) {
        #pragma unroll
        for (int n = 0; n < 4; ++n) {
            #pragma unroll
            for (int r = 0; r < 4; ++r) {
                int row = brow + wr * 64 + i * 16 + (lane >> 4) * 4 + r;
                int col = wc * 64 + n * 16 + l15;
                if (row < N_NODES) {
                    float v = acc[i][n][r];
                    if (act) v = tanhf(v);
                    H[(long)row * OUT_F + col] = f2bf(v);
                }
            }
        }
    }
}

// ---- Kernel 3: SpMM. One wave per row; 32 edges per iteration.
//      Slot q (lane>>4) owns 8 consecutive edges. The 8 row-gathers are
//      issued as 8 asm-volatile global_load_dwordx4 (SGPR base + 32-bit
//      byte voffset) so the compiler CANNOT serialize them -> 8KB/wave
//      in flight. One s_waitcnt vmcnt(0) + sched_barrier(0) before FMAs
//      (rule #18). Value-predicated head/tail as in R5 (verified). ----
__global__ __launch_bounds__(256, 4) void k_spmm(const int* __restrict__ row_ptr,
                                                 const int* __restrict__ ecol,
                                                 const float* __restrict__ eval,
                                                 const unsigned int* __restrict__ h32, // bf16x2 per dword
                                                 float* __restrict__ out) {
    const int lane = threadIdx.x & 63;
    const int w    = threadIdx.x >> 6;
    const int r    = blockIdx.x * 4 + w;
    if (r >= N_NODES) return;

    const int      q   = lane >> 4;           // edge slot 0..3 (8 consecutive edges)
    const unsigned dqb = (unsigned)(lane & 15) * 16u;  // byte offset within 256B row

    const int s = __builtin_amdgcn_readfirstlane(row_ptr[r]);
    const int e = __builtin_amdgcn_readfirstlane(row_ptr[r + 1]);
    const unsigned rowlen = (unsigned)(e - s);

    float f0 = 0.f, f1 = 0.f, f2 = 0.f, f3 = 0.f;
    float f4 = 0.f, f5 = 0.f, f6 = 0.f, f7 = 0.f;

    const int j0 = s & ~3;            // 16B-align all int4/float4 edge loads
    for (int j = j0; j < e; j += 32) {
        const int b = j + q * 8;      // this slot's 8 edges

        int4   c0, c1;
        float4 v0, v1;
        if (b + 8 <= N_EDGES) {       // fast path: aligned vector loads at b
            c0 = *(const int4*)(ecol + b);
            c1 = *(const int4*)(ecol + b + 4);
            v0 = *(const float4*)(eval + b);
            v1 = *(const float4*)(eval + b + 4);
        } else {                      // rare: last iteration of last row only
            int idx[8];
            #pragma unroll
            for (int t = 0; t < 8; ++t) idx[t] = min(b + t, N_EDGES - 1);
            c0.x = ecol[idx[0]]; c0.y = ecol[idx[1]]; c0.z = ecol[idx[2]]; c0.w = ecol[idx[3]];
            c1.x = ecol[idx[4]]; c1.y = ecol[idx[5]]; c1.z = ecol[idx[6]]; c1.w = ecol[idx[7]];
            v0.x = eval[idx[0]]; v0.y = eval[idx[1]]; v0.z = eval[idx[2]]; v0.w = eval[idx[3]];
            v1.x = eval[idx[4]]; v1.y = eval[idx[5]]; v1.z = eval[idx[6]]; v1.w = eval[idx[7]];
        }

        // validity: (unsigned)(b+t-s) < rowlen  (one compare per edge)
        float vv[8];
        vv[0] = ((unsigned)(b + 0 - s) < rowlen) ? v0.x : 0.f;
        vv[1] = ((unsigned)(b + 1 - s) < rowlen) ? v0.y : 0.f;
        vv[2] = ((unsigned)(b + 2 - s) < rowlen) ? v0.z : 0.f;
        vv[3] = ((unsigned)(b + 3 - s) < rowlen) ? v0.w : 0.f;
        vv[4] = ((unsigned)(b + 4 - s) < rowlen) ? v1.x : 0.f;
        vv[5] = ((unsigned)(b + 5 - s) < rowlen) ? v1.y : 0.f;
        vv[6] = ((unsigned)(b + 6 - s) < rowlen) ? v1.z : 0.f;
        vv[7] = ((unsigned)(b + 7 - s) < rowlen) ? v1.w : 0.f;

        // byte offsets into h: col*256 + dqb
        const unsigned o0 = dqb + (((unsigned)c0.x) << 8);
        const unsigned o1 = dqb + (((unsigned)c0.y) << 8);
        const unsigned o2 = dqb + (((unsigned)c0.z) << 8);
        const unsigned o3 = dqb + (((unsigned)c0.w) << 8);
        const unsigned o4 = dqb + (((unsigned)c1.x) << 8);
        const unsigned o5 = dqb + (((unsigned)c1.y) << 8);
        const unsigned o6 = dqb + (((unsigned)c1.z) << 8);
        const unsigned o7 = dqb + (((unsigned)c1.w) << 8);

        u32x4 g0, g1, g2, g3, g4, g5, g6, g7;
        asm volatile("global_load_dwordx4 %0, %1, %2" : "=v"(g0) : "v"(o0), "s"(h32));
        asm volatile("global_load_dwordx4 %0, %1, %2" : "=v"(g1) : "v"(o1), "s"(h32));
        asm volatile("global_load_dwordx4 %0, %1, %2" : "=v"(g2) : "v"(o2), "s"(h32));
        asm volatile("global_load_dwordx4 %0, %1, %2" : "=v"(g3) : "v"(o3), "s"(h32));
        asm volatile("global_load_dwordx4 %0, %1, %2" : "=v"(g4) : "v"(o4), "s"(h32));
        asm volatile("global_load_dwordx4 %0, %1, %2" : "=v"(g5) : "v"(o5), "s"(h32));
        asm volatile("global_load_dwordx4 %0, %1, %2" : "=v"(g6) : "v"(o6), "s"(h32));
        asm volatile("global_load_dwordx4 %0, %1, %2" : "=v"(g7) : "v"(o7), "s"(h32));
        asm volatile("s_waitcnt vmcnt(0)" ::: "memory");
        __builtin_amdgcn_sched_barrier(0);

        #define EDGE_FMA(G, V)                                          \
            f0 = fmaf(V, __uint_as_float(G.x << 16), f0);               \
            f1 = fmaf(V, __uint_as_float(G.x & 0xffff0000u), f1);       \
            f2 = fmaf(V, __uint_as_float(G.y << 16), f2);               \
            f3 = fmaf(V, __uint_as_float(G.y & 0xffff0000u), f3);       \
            f4 = fmaf(V, __uint_as_float(G.z << 16), f4);               \
            f5 = fmaf(V, __uint_as_float(G.z & 0xffff0000u), f5);       \
            f6 = fmaf(V, __uint_as_float(G.w << 16), f6);               \
            f7 = fmaf(V, __uint_as_float(G.w & 0xffff0000u), f7);
        EDGE_FMA(g0, vv[0]) EDGE_FMA(g1, vv[1]) EDGE_FMA(g2, vv[2]) EDGE_FMA(g3, vv[3])
        EDGE_FMA(g4, vv[4]) EDGE_FMA(g5, vv[5]) EDGE_FMA(g6, vv[6]) EDGE_FMA(g7, vv[7])
        #undef EDGE_FMA
    }

    // reduce the 4 edge slots: lanes l, l+16, l+32, l+48 hold the same columns
    #pragma unroll
    for (int mask = 16; mask <= 32; mask <<= 1) {
        f0 += __shfl_xor(f0, mask);
        f1 += __shfl_xor(f1, mask);
        f2 += __shfl_xor(f2, mask);
        f3 += __shfl_xor(f3, mask);
        f4 += __shfl_xor(f4, mask);
        f5 += __shfl_xor(f5, mask);
        f6 += __shfl_xor(f6, mask);
        f7 += __shfl_xor(f7, mask);
    }

    if (q == 0) {
        float* dst = out + (long)r * OUT_F + (dqb >> 3) * 4;  // (lane&15)*8 cols
        float4 o0v; o0v.x = f0; o0v.y = f1; o0v.z = f2; o0v.w = f3;
        float4 o1v; o1v.x = f4; o1v.y = f5; o1v.z = f6; o1v.w = f7;
        *(float4*)dst       = o0v;
        *(float4*)(dst + 4) = o1v;
    }
}

extern "C" void kernel_launch(void* const* d_in, const int* in_sizes, int n_in,
                              void* d_out, int out_size, void* d_ws, size_t ws_size,
                              hipStream_t stream) {
    const float* features = (const float*)d_in[0];
    const float* weight   = (const float*)d_in[1];
    const int*   erow     = (const int*)d_in[2];
    const int*   ecol     = (const int*)d_in[3];
    const float* evalp    = (const float*)d_in[4];
    const int*   activep  = (const int*)d_in[5];
    float* out = (float*)d_out;

    char* ws = (char*)d_ws;
    unsigned short* H  = (unsigned short*)ws;                         // 25,600,000 B
    unsigned short* Wt = (unsigned short*)(ws + 25600000);            //     65,536 B
    int* row_ptr       = (int*)(ws + 25600000 + 65536);               //    400,004 B

    k_wt    <<<128, 256, 0, stream>>>(weight, Wt);
    k_rowptr<<<(N_EDGES + 255) / 256, 256, 0, stream>>>(erow, row_ptr);
    k_gemm  <<<(N_NODES + 127) / 128, 256, 0, stream>>>(features, Wt, H, activep);
    k_spmm  <<<(N_NODES + 3) / 4, 256, 0, stream>>>(row_ptr, ecol, evalp,
                                                    (const unsigned int*)H, out);
}

// Round 7
// 172.402 us; speedup vs baseline: 1.2297x; 1.1695x over previous
//
#include <hip/hip_runtime.h>
#include <hip/hip_bf16.h>

#define N_NODES 100000
#define N_EDGES 3200000
#define IN_F 256
#define OUT_F 128

typedef __attribute__((ext_vector_type(8))) short bf16x8;
typedef __attribute__((ext_vector_type(4))) float f32x4;

__device__ __forceinline__ unsigned short f2bf(float f) {
    unsigned int u = __float_as_uint(f);
    u += 0x7fffu + ((u >> 16) & 1u);   // round-to-nearest-even
    return (unsigned short)(u >> 16);
}

// ---- Kernel 0: fused init: Wt transpose+convert AND CSR row_ptr ----
__global__ void k_init(const float* __restrict__ W, unsigned short* __restrict__ Wt,
                       const int* __restrict__ erow, int* __restrict__ row_ptr) {
    int e = blockIdx.x * 256 + threadIdx.x;
    if (e < IN_F * OUT_F) {            // W [256][128] f32 -> Wt [128][256] bf16
        int k = e >> 7;
        int c = e & 127;
        Wt[c * IN_F + k] = f2bf(W[e]);
    }
    if (e >= N_EDGES) return;
    int r = erow[e];
    int rprev = (e == 0) ? -1 : erow[e - 1];
    for (int rr = rprev + 1; rr <= r; ++rr) row_ptr[rr] = e;
    if (e == N_EDGES - 1) {
        for (int rr = r + 1; rr <= N_NODES; ++rr) row_ptr[rr] = N_EDGES;
    }
}

// ---- Kernel 2: H = tanh(A @ W) in bf16. 128x128 tile, 4 waves (2x2).
//      A-loads software-pipelined one k-step ahead (raw float4 pipeline regs,
//      convert at use time so the vmcnt wait lands after a full MFMA phase).
//      Fast tanh via __expf. ----
__global__ __launch_bounds__(256) void k_gemm(const float* __restrict__ A,
                                              const unsigned short* __restrict__ Wt,
                                              unsigned short* __restrict__ H,
                                              const int* __restrict__ activep) {
    const int tid  = threadIdx.x;
    const int lane = tid & 63;
    const int wid  = tid >> 6;
    const int wr   = wid >> 1;   // 0..1 row-half
    const int wc   = wid & 1;    // 0..1 col-half
    const int brow = blockIdx.x * 128;
    const int l15  = lane & 15;
    const int lk   = (lane >> 4) * 8;  // k-offset of this lane's 8 elems

    // per-row A base pointers (constant over k)
    const float* ap[4];
    #pragma unroll
    for (int i = 0; i < 4; ++i) {
        int row = brow + wr * 64 + i * 16 + l15;
        if (row > N_NODES - 1) row = N_NODES - 1;   // clamp OOB reads
        ap[i] = A + (long)row * IN_F + lk;
    }
    // B base: b[n] = bp + n*16*IN_F + k0
    const unsigned short* bp = Wt + (long)(wc * 64 + l15) * IN_F + lk;

    f32x4 acc[4][4] = {};

    // prologue: raw A loads for k0 = 0
    float4 f0[4], f1[4];
    #pragma unroll
    for (int i = 0; i < 4; ++i) {
        f0[i] = *(const float4*)(ap[i]);
        f1[i] = *(const float4*)(ap[i] + 4);
    }

    for (int k0 = 0; k0 < IN_F; k0 += 32) {
        const int kn = k0 + 32;
        // issue next k-step's A loads first (pipeline)
        float4 n0[4], n1[4];
        if (kn < IN_F) {
            #pragma unroll
            for (int i = 0; i < 4; ++i) {
                n0[i] = *(const float4*)(ap[i] + kn);
                n1[i] = *(const float4*)(ap[i] + kn + 4);
            }
        }
        // convert current A to bf16 frags
        bf16x8 a[4];
        #pragma unroll
        for (int i = 0; i < 4; ++i) {
            bf16x8 v;
            v[0] = (short)f2bf(f0[i].x); v[1] = (short)f2bf(f0[i].y);
            v[2] = (short)f2bf(f0[i].z); v[3] = (short)f2bf(f0[i].w);
            v[4] = (short)f2bf(f1[i].x); v[5] = (short)f2bf(f1[i].y);
            v[6] = (short)f2bf(f1[i].z); v[7] = (short)f2bf(f1[i].w);
            a[i] = v;
        }
        // B frags (Wt is L2/L3-resident)
        bf16x8 b[4];
        #pragma unroll
        for (int n = 0; n < 4; ++n)
            b[n] = *(const bf16x8*)(bp + (long)n * 16 * IN_F + k0);

        #pragma unroll
        for (int i = 0; i < 4; ++i)
            #pragma unroll
            for (int n = 0; n < 4; ++n)
                acc[i][n] = __builtin_amdgcn_mfma_f32_16x16x32_bf16(a[i], b[n], acc[i][n], 0, 0, 0);

        if (kn < IN_F) {
            #pragma unroll
            for (int i = 0; i < 4; ++i) { f0[i] = n0[i]; f1[i] = n1[i]; }
        }
    }

    const int act = *activep;
    // C/D layout: col = lane&15, row = (lane>>4)*4 + reg   [m89-verified]
    #pragma unroll
    for (int i = 0; i < 4; ++i) {
        #pragma unroll
        for (int n = 0; n < 4; ++n) {
            #pragma unroll
            for (int r = 0; r < 4; ++r) {
                int row = brow + wr * 64 + i * 16 + (lane >> 4) * 4 + r;
                int col = wc * 64 + n * 16 + l15;
                if (row < N_NODES) {
                    float v = acc[i][n][r];
                    if (act) {
                        // tanh(v) = 1 - 2/(e^{2v}+1)
                        float t = __expf(2.0f * v);
                        v = 1.0f - __fdividef(2.0f, t + 1.0f);
                    }
                    H[(long)row * OUT_F + col] = f2bf(v);
                }
            }
        }
    }
}

// ---- Kernel 3: SpMM (R3-exact, best measured: 108us, VGPR 24, occ 74%).
//      One wave per row. 16 lanes cover one edge's 256B row -> one uint4
//      gather instruction covers 4 edges. 16 edges/iter. Invalid lanes
//      clamp the edge index to e-1 so dead gathers coalesce with live ones
//      (no extra traffic). shfl_xor(16/32) butterfly at row end. ----
__global__ __launch_bounds__(256) void k_spmm(const int* __restrict__ row_ptr,
                                              const int* __restrict__ ecol,
                                              const float* __restrict__ eval,
                                              const unsigned int* __restrict__ h32, // bf16x2 per dword
                                              float* __restrict__ out) {
    const int lane = threadIdx.x & 63;
    const int w    = threadIdx.x >> 6;
    const int r    = blockIdx.x * 4 + w;
    if (r >= N_NODES) return;

    const int q  = lane >> 4;         // edge slot 0..3 within wave
    const int dq = (lane & 15) * 4;   // dword offset within h row (0..60)

    const int s = __builtin_amdgcn_readfirstlane(row_ptr[r]);
    const int e = __builtin_amdgcn_readfirstlane(row_ptr[r + 1]);

    const unsigned int* hq = h32 + dq;

    float f0 = 0.f, f1 = 0.f, f2 = 0.f, f3 = 0.f;
    float f4 = 0.f, f5 = 0.f, f6 = 0.f, f7 = 0.f;

    for (int j = s; j < e; j += 16) {
        int   cc[4];
        float vv[4];
        #pragma unroll
        for (int u = 0; u < 4; ++u) {
            const int want = j + u * 4 + q;
            const int idx  = min(want, e - 1);     // always in-bounds (e>s here)
            cc[u] = ecol[idx];
            vv[u] = (want < e) ? eval[idx] : 0.f;  // predicate via value, not branch
        }
        uint4 g[4];
        #pragma unroll
        for (int u = 0; u < 4; ++u)
            g[u] = *(const uint4*)(hq + (((unsigned)cc[u]) << 6));
        #pragma unroll
        for (int u = 0; u < 4; ++u) {
            const float v = vv[u];
            f0 = fmaf(v, __uint_as_float(g[u].x << 16), f0);
            f1 = fmaf(v, __uint_as_float(g[u].x & 0xffff0000u), f1);
            f2 = fmaf(v, __uint_as_float(g[u].y << 16), f2);
            f3 = fmaf(v, __uint_as_float(g[u].y & 0xffff0000u), f3);
            f4 = fmaf(v, __uint_as_float(g[u].z << 16), f4);
            f5 = fmaf(v, __uint_as_float(g[u].z & 0xffff0000u), f5);
            f6 = fmaf(v, __uint_as_float(g[u].w << 16), f6);
            f7 = fmaf(v, __uint_as_float(g[u].w & 0xffff0000u), f7);
        }
    }

    // reduce the 4 edge slots: lanes l, l+16, l+32, l+48 hold the same columns
    #pragma unroll
    for (int mask = 16; mask <= 32; mask <<= 1) {
        f0 += __shfl_xor(f0, mask);
        f1 += __shfl_xor(f1, mask);
        f2 += __shfl_xor(f2, mask);
        f3 += __shfl_xor(f3, mask);
        f4 += __shfl_xor(f4, mask);
        f5 += __shfl_xor(f5, mask);
        f6 += __shfl_xor(f6, mask);
        f7 += __shfl_xor(f7, mask);
    }

    if (q == 0) {
        float* dst = out + (long)r * OUT_F + dq * 2;  // dq*2 = (lane&15)*8 cols
        float4 o0; o0.x = f0; o0.y = f1; o0.z = f2; o0.w = f3;
        float4 o1; o1.x = f4; o1.y = f5; o1.z = f6; o1.w = f7;
        *(float4*)dst       = o0;
        *(float4*)(dst + 4) = o1;
    }
}

extern "C" void kernel_launch(void* const* d_in, const int* in_sizes, int n_in,
                              void* d_out, int out_size, void* d_ws, size_t ws_size,
                              hipStream_t stream) {
    const float* features = (const float*)d_in[0];
    const float* weight   = (const float*)d_in[1];
    const int*   erow     = (const int*)d_in[2];
    const int*   ecol     = (const int*)d_in[3];
    const float* evalp    = (const float*)d_in[4];
    const int*   activep  = (const int*)d_in[5];
    float* out = (float*)d_out;

    char* ws = (char*)d_ws;
    unsigned short* H  = (unsigned short*)ws;                         // 25,600,000 B
    unsigned short* Wt = (unsigned short*)(ws + 25600000);            //     65,536 B
    int* row_ptr       = (int*)(ws + 25600000 + 65536);               //    400,004 B

    k_init  <<<(N_EDGES + 255) / 256, 256, 0, stream>>>(weight, Wt, erow, row_ptr);
    k_gemm  <<<(N_NODES + 127) / 128, 256, 0, stream>>>(features, Wt, H, activep);
    k_spmm  <<<(N_NODES + 3) / 4, 256, 0, stream>>>(row_ptr, ecol, evalp,
                                                    (const unsigned int*)H, out);
}

// Round 8
// 149.288 us; speedup vs baseline: 1.4201x; 1.1548x over previous
//
#include <hip/hip_runtime.h>
#include <hip/hip_bf16.h>

#define N_NODES 100000
#define N_EDGES 3200000
#define IN_F 256
#define OUT_F 128

typedef __attribute__((ext_vector_type(8))) short bf16x8;
typedef __attribute__((ext_vector_type(4))) float f32x4;

__device__ __forceinline__ unsigned short f2bf(float f) {
    unsigned int u = __float_as_uint(f);
    u += 0x7fffu + ((u >> 16) & 1u);   // round-to-nearest-even
    return (unsigned short)(u >> 16);
}

__device__ __forceinline__ short cvt_bf16(float f) {
    __hip_bfloat16 b = (__hip_bfloat16)f;      // native cvt (pairs -> v_cvt_pk_bf16_f32)
    return *reinterpret_cast<short*>(&b);
}

// ---- Kernel 0: fused init: Wt transpose+convert AND CSR row_ptr ----
__global__ void k_init(const float* __restrict__ W, unsigned short* __restrict__ Wt,
                       const int* __restrict__ erow, int* __restrict__ row_ptr) {
    int e = blockIdx.x * 256 + threadIdx.x;
    if (e < IN_F * OUT_F) {            // W [256][128] f32 -> Wt [128][256] bf16
        int k = e >> 7;
        int c = e & 127;
        Wt[c * IN_F + k] = f2bf(W[e]);
    }
    if (e >= N_EDGES) return;
    int r = erow[e];
    int rprev = (e == 0) ? -1 : erow[e - 1];
    for (int rr = rprev + 1; rr <= r; ++rr) row_ptr[rr] = e;
    if (e == N_EDGES - 1) {
        for (int rr = r + 1; rr <= N_NODES; ++rr) row_ptr[rr] = N_EDGES;
    }
}

// ---- Kernel 2: H8 = quant_int8(tanh(A @ W)). 128x128 tile, 4 waves (2x2).
//      A-loads software-pipelined one k-step ahead. Fast tanh via __expf.
//      act=1: scale 127 (tanh in [-1,1]); act=0: scale 16. ----
__global__ __launch_bounds__(256) void k_gemm(const float* __restrict__ A,
                                              const unsigned short* __restrict__ Wt,
                                              signed char* __restrict__ H8,
                                              const int* __restrict__ activep) {
    const int tid  = threadIdx.x;
    const int lane = tid & 63;
    const int wid  = tid >> 6;
    const int wr   = wid >> 1;   // 0..1 row-half
    const int wc   = wid & 1;    // 0..1 col-half
    const int brow = blockIdx.x * 128;
    const int l15  = lane & 15;
    const int lk   = (lane >> 4) * 8;  // k-offset of this lane's 8 elems

    // per-row A base pointers (constant over k)
    const float* ap[4];
    #pragma unroll
    for (int i = 0; i < 4; ++i) {
        int row = brow + wr * 64 + i * 16 + l15;
        if (row > N_NODES - 1) row = N_NODES - 1;   // clamp OOB reads
        ap[i] = A + (long)row * IN_F + lk;
    }
    // B base: b[n] = bp + n*16*IN_F + k0
    const unsigned short* bp = Wt + (long)(wc * 64 + l15) * IN_F + lk;

    f32x4 acc[4][4] = {};

    // prologue: raw A loads for k0 = 0
    float4 f0[4], f1[4];
    #pragma unroll
    for (int i = 0; i < 4; ++i) {
        f0[i] = *(const float4*)(ap[i]);
        f1[i] = *(const float4*)(ap[i] + 4);
    }

    for (int k0 = 0; k0 < IN_F; k0 += 32) {
        const int kn = k0 + 32;
        // issue next k-step's A loads first (pipeline)
        float4 n0[4], n1[4];
        if (kn < IN_F) {
            #pragma unroll
            for (int i = 0; i < 4; ++i) {
                n0[i] = *(const float4*)(ap[i] + kn);
                n1[i] = *(const float4*)(ap[i] + kn + 4);
            }
        }
        // convert current A to bf16 frags (native cvt, packs to cvt_pk)
        bf16x8 a[4];
        #pragma unroll
        for (int i = 0; i < 4; ++i) {
            bf16x8 v;
            v[0] = cvt_bf16(f0[i].x); v[1] = cvt_bf16(f0[i].y);
            v[2] = cvt_bf16(f0[i].z); v[3] = cvt_bf16(f0[i].w);
            v[4] = cvt_bf16(f1[i].x); v[5] = cvt_bf16(f1[i].y);
            v[6] = cvt_bf16(f1[i].z); v[7] = cvt_bf16(f1[i].w);
            a[i] = v;
        }
        // B frags (Wt is L2/L3-resident)
        bf16x8 b[4];
        #pragma unroll
        for (int n = 0; n < 4; ++n)
            b[n] = *(const bf16x8*)(bp + (long)n * 16 * IN_F + k0);

        #pragma unroll
        for (int i = 0; i < 4; ++i)
            #pragma unroll
            for (int n = 0; n < 4; ++n)
                acc[i][n] = __builtin_amdgcn_mfma_f32_16x16x32_bf16(a[i], b[n], acc[i][n], 0, 0, 0);

        if (kn < IN_F) {
            #pragma unroll
            for (int i = 0; i < 4; ++i) { f0[i] = n0[i]; f1[i] = n1[i]; }
        }
    }

    const int act = *activep;
    const float qs = act ? 127.0f : 16.0f;
    // C/D layout: col = lane&15, row = (lane>>4)*4 + reg   [m89-verified]
    #pragma unroll
    for (int i = 0; i < 4; ++i) {
        #pragma unroll
        for (int n = 0; n < 4; ++n) {
            #pragma unroll
            for (int r = 0; r < 4; ++r) {
                int row = brow + wr * 64 + i * 16 + (lane >> 4) * 4 + r;
                int col = wc * 64 + n * 16 + l15;
                if (row < N_NODES) {
                    float v = acc[i][n][r];
                    if (act) {
                        // tanh(v) = 1 - 2/(e^{2v}+1)
                        float t = __expf(2.0f * v);
                        v = 1.0f - __fdividef(2.0f, t + 1.0f);
                    }
                    float q = v * qs;
                    q = fminf(fmaxf(q, -127.0f), 127.0f);
                    H8[(long)row * OUT_F + col] = (signed char)__float2int_rn(q);
                }
            }
        }
    }
}

// ---- Kernel 3: SpMM over int8 h (128B rows -> half the gather traffic).
//      One wave per row. 16 lanes x 8B (uint2) cover one edge's 128B row;
//      one gather instruction covers 4 edges. 16 edges/iter. Invalid lanes
//      clamp the edge index to e-1 so dead gathers coalesce with live ones.
//      Unpack: bfe_i32 + cvt_f32_i32; scale folded into edge val.
//      shfl_xor(16/32) butterfly at row end. ----
__global__ __launch_bounds__(256) void k_spmm(const int* __restrict__ row_ptr,
                                              const int* __restrict__ ecol,
                                              const float* __restrict__ eval,
                                              const signed char* __restrict__ h8,
                                              const int* __restrict__ activep,
                                              float* __restrict__ out) {
    const int lane = threadIdx.x & 63;
    const int w    = threadIdx.x >> 6;
    const int r    = blockIdx.x * 4 + w;
    if (r >= N_NODES) return;

    const int q  = lane >> 4;         // edge slot 0..3 within wave
    const int l15 = lane & 15;

    const int s = __builtin_amdgcn_readfirstlane(row_ptr[r]);
    const int e = __builtin_amdgcn_readfirstlane(row_ptr[r + 1]);
    const int act = __builtin_amdgcn_readfirstlane(*activep);
    const float invs = act ? (1.0f / 127.0f) : (1.0f / 16.0f);

    // lane's 8 bytes within a 128B h row
    const signed char* hq = h8 + l15 * 8;

    float f0 = 0.f, f1 = 0.f, f2 = 0.f, f3 = 0.f;
    float f4 = 0.f, f5 = 0.f, f6 = 0.f, f7 = 0.f;

    for (int j = s; j < e; j += 16) {
        int   cc[4];
        float vv[4];
        #pragma unroll
        for (int u = 0; u < 4; ++u) {
            const int want = j + u * 4 + q;
            const int idx  = min(want, e - 1);     // always in-bounds (e>s here)
            cc[u] = ecol[idx];
            vv[u] = (want < e) ? eval[idx] * invs : 0.f;  // predicate + scale
        }
        uint2 g[4];
        #pragma unroll
        for (int u = 0; u < 4; ++u)
            g[u] = *(const uint2*)(hq + (((unsigned)cc[u]) << 7));
        #pragma unroll
        for (int u = 0; u < 4; ++u) {
            const float v = vv[u];
            const unsigned x = g[u].x, y = g[u].y;
            f0 = fmaf(v, (float)((signed char)(x      )), f0);
            f1 = fmaf(v, (float)((signed char)(x >>  8)), f1);
            f2 = fmaf(v, (float)((signed char)(x >> 16)), f2);
            f3 = fmaf(v, (float)((int)x >> 24),           f3);
            f4 = fmaf(v, (float)((signed char)(y      )), f4);
            f5 = fmaf(v, (float)((signed char)(y >>  8)), f5);
            f6 = fmaf(v, (float)((signed char)(y >> 16)), f6);
            f7 = fmaf(v, (float)((int)y >> 24),           f7);
        }
    }

    // reduce the 4 edge slots: lanes l, l+16, l+32, l+48 hold the same columns
    #pragma unroll
    for (int mask = 16; mask <= 32; mask <<= 1) {
        f0 += __shfl_xor(f0, mask);
        f1 += __shfl_xor(f1, mask);
        f2 += __shfl_xor(f2, mask);
        f3 += __shfl_xor(f3, mask);
        f4 += __shfl_xor(f4, mask);
        f5 += __shfl_xor(f5, mask);
        f6 += __shfl_xor(f6, mask);
        f7 += __shfl_xor(f7, mask);
    }

    if (q == 0) {
        float* dst = out + (long)r * OUT_F + l15 * 8;
        float4 o0; o0.x = f0; o0.y = f1; o0.z = f2; o0.w = f3;
        float4 o1; o1.x = f4; o1.y = f5; o1.z = f6; o1.w = f7;
        *(float4*)dst       = o0;
        *(float4*)(dst + 4) = o1;
    }
}

extern "C" void kernel_launch(void* const* d_in, const int* in_sizes, int n_in,
                              void* d_out, int out_size, void* d_ws, size_t ws_size,
                              hipStream_t stream) {
    const float* features = (const float*)d_in[0];
    const float* weight   = (const float*)d_in[1];
    const int*   erow     = (const int*)d_in[2];
    const int*   ecol     = (const int*)d_in[3];
    const float* evalp    = (const float*)d_in[4];
    const int*   activep  = (const int*)d_in[5];
    float* out = (float*)d_out;

    char* ws = (char*)d_ws;
    signed char* H8    = (signed char*)ws;                            // 12,800,000 B
    unsigned short* Wt = (unsigned short*)(ws + 12800000);            //     65,536 B
    int* row_ptr       = (int*)(ws + 12800000 + 65536);               //    400,004 B

    k_init  <<<(N_EDGES + 255) / 256, 256, 0, stream>>>(weight, Wt, erow, row_ptr);
    k_gemm  <<<(N_NODES + 127) / 128, 256, 0, stream>>>(features, Wt, H8, activep);
    k_spmm  <<<(N_NODES + 3) / 4, 256, 0, stream>>>(row_ptr, ecol, evalp,
                                                    H8, activep, out);
}